// Round 1
// baseline (579.656 us; speedup 1.0000x reference)
//
#include <hip/hip_runtime.h>

#define T_DIM 2048
#define N_DIM 256
#define K_DIM 256
#define C_DIM 40
#define CHUNK 32
#define NCHUNK 64            // T_DIM / CHUNK

#define LOG2E_F 1.44269504088896340736f
#define LN2_F   0.69314718055994530942f
#define NEGBIG  (-1.0e30f)

#if __has_builtin(__builtin_amdgcn_exp2f)
__device__ __forceinline__ float fexp2(float x) { return __builtin_amdgcn_exp2f(x); }
#else
__device__ __forceinline__ float fexp2(float x) { return exp2f(x); }
#endif
#if __has_builtin(__builtin_amdgcn_logf)
__device__ __forceinline__ float flog2(float x) { return __builtin_amdgcn_logf(x); }
#else
__device__ __forceinline__ float flog2(float x) { return log2f(x); }
#endif
#if __has_builtin(__builtin_amdgcn_rcpf)
__device__ __forceinline__ float frcp(float x) { return __builtin_amdgcn_rcpf(x); }
#else
__device__ __forceinline__ float frcp(float x) { return 1.0f / x; }
#endif

// ---------------------------------------------------------------------------
// K1: y[row][c] = 5*tanh(dot(x[row], W[c]) + b[c]);  one thread per row.
// x rows streamed as float4 per lane; W/b read with wave-uniform indices
// (compiler scalarizes to s_load -> K$), 40 fp32 accumulators per thread.
// ---------------------------------------------------------------------------
__global__ __launch_bounds__(256) void k1_gemm_tanh(
    const float* __restrict__ x, const float* __restrict__ W,
    const float* __restrict__ b, float* __restrict__ y)
{
    const size_t row = (size_t)blockIdx.x * 256 + threadIdx.x;
    const float4* __restrict__ xr = (const float4*)(x + row * K_DIM);

    float acc[C_DIM];
#pragma unroll
    for (int c = 0; c < C_DIM; ++c) acc[c] = b[c];

    // software-pipelined over 16 k-tiles of 16 floats (4 float4) each
    float4 a0 = xr[0], a1 = xr[1], a2 = xr[2], a3 = xr[3];
#pragma unroll 1
    for (int kt = 0; kt < 16; ++kt) {
        const int nx = (kt + 1 < 16) ? (kt + 1) * 4 : 0;
        float4 b0 = xr[nx + 0], b1 = xr[nx + 1], b2 = xr[nx + 2], b3 = xr[nx + 3];
        const float* __restrict__ wb = W + kt * 16;
#pragma unroll
        for (int c = 0; c < C_DIM; ++c) {
            const float4 w0 = *(const float4*)(wb + c * K_DIM + 0);
            const float4 w1 = *(const float4*)(wb + c * K_DIM + 4);
            const float4 w2 = *(const float4*)(wb + c * K_DIM + 8);
            const float4 w3 = *(const float4*)(wb + c * K_DIM + 12);
            float s = acc[c];
            s = fmaf(a0.x, w0.x, s); s = fmaf(a0.y, w0.y, s);
            s = fmaf(a0.z, w0.z, s); s = fmaf(a0.w, w0.w, s);
            s = fmaf(a1.x, w1.x, s); s = fmaf(a1.y, w1.y, s);
            s = fmaf(a1.z, w1.z, s); s = fmaf(a1.w, w1.w, s);
            s = fmaf(a2.x, w2.x, s); s = fmaf(a2.y, w2.y, s);
            s = fmaf(a2.z, w2.z, s); s = fmaf(a2.w, w2.w, s);
            s = fmaf(a3.x, w3.x, s); s = fmaf(a3.y, w3.y, s);
            s = fmaf(a3.z, w3.z, s); s = fmaf(a3.w, w3.w, s);
            acc[c] = s;
        }
        a0 = b0; a1 = b1; a2 = b2; a3 = b3;
    }

    float out[C_DIM];
#pragma unroll
    for (int c = 0; c < C_DIM; ++c) {
        const float v = acc[c];
        const float e = fexp2(fabsf(v) * (2.0f * LOG2E_F)); // e^(2|v|)
        const float t = 1.0f - 2.0f * frcp(e + 1.0f);       // tanh(|v|)
        out[c] = 5.0f * copysignf(t, v);
    }
    float4* __restrict__ yo = (float4*)(y + row * C_DIM);
#pragma unroll
    for (int q = 0; q < 10; ++q)
        yo[q] = make_float4(out[4 * q + 0], out[4 * q + 1],
                            out[4 * q + 2], out[4 * q + 3]);
}

// ---------------------------------------------------------------------------
// K2: per (chain n, chunk g) propagate the 8x8 log-semiring matrix through
// 32 steps. 8 lanes per task; lane c holds column M[:,c] -> inner loop is
// fully lane-local. Base-2 domain (scores pre-scaled by log2(e)).
// Writes cmat[g][j][n][c] = M_g[c? no: stored target[g][b][n][a] = M[a][b].
// ---------------------------------------------------------------------------
__global__ __launch_bounds__(256) void k2_chunks(
    const float* __restrict__ y, float* __restrict__ cmat)
{
    const int tid  = threadIdx.x;
    const int wave = tid >> 6;
    const int lane = tid & 63;
    const int task = lane >> 3;   // 8 tasks per wave
    const int c    = lane & 7;    // column owned by this lane
    const int g    = blockIdx.x & (NCHUNK - 1);
    const int n    = ((blockIdx.x >> 6) << 5) + (wave << 3) + task;

    float col[8];
#pragma unroll
    for (int j = 0; j < 8; ++j) col[j] = (j == c) ? 0.0f : NEGBIG;

    const float* __restrict__ yp =
        y + ((size_t)(g * CHUNK) * N_DIM + (size_t)n) * C_DIM;

#pragma unroll 1
    for (int s = 0; s < CHUNK; ++s) {
        float sc[C_DIM];
        const float4* p4 = (const float4*)yp;
#pragma unroll
        for (int q = 0; q < 10; ++q) {
            const float4 v = p4[q];
            sc[4 * q + 0] = v.x * LOG2E_F;
            sc[4 * q + 1] = v.y * LOG2E_F;
            sc[4 * q + 2] = v.z * LOG2E_F;
            sc[4 * q + 3] = v.w * LOG2E_F;
        }
        float nc[8];
#pragma unroll
        for (int d = 0; d < 4; ++d) {          // dense rows: lse over 8
            float tv[8];
#pragma unroll
            for (int j = 0; j < 8; ++j) tv[j] = sc[d * 8 + j] + col[j];
            float m = tv[0];
#pragma unroll
            for (int j = 1; j < 8; ++j) m = fmaxf(m, tv[j]);
            float ss = 0.0f;
#pragma unroll
            for (int j = 0; j < 8; ++j) ss += fexp2(tv[j] - m);
            nc[d] = m + flog2(ss);
        }
#pragma unroll
        for (int i = 0; i < 4; ++i) {          // sparse rows: logaddexp of 2
            const float a  = sc[32 + i] + col[i];
            const float bb = sc[36 + i] + col[i + 4];
            const float m  = fmaxf(a, bb);
            const float ss = fexp2(a - m) + fexp2(bb - m);
            nc[4 + i] = m + flog2(ss);
        }
#pragma unroll
        for (int j = 0; j < 8; ++j) col[j] = nc[j];
        yp += (size_t)N_DIM * C_DIM;
    }
    // store M[j][c] at cmat[((g*8 + c)*N_DIM + n)*8 + j]  (contig 8 per lane)
    float* __restrict__ op = cmat + (((size_t)g * 8 + c) * N_DIM + n) * 8;
#pragma unroll
    for (int j = 0; j < 8; ++j) op[j] = col[j];
}

// ---------------------------------------------------------------------------
// K3: per chain, fold the 64 chunk matrices into logZ via log-semiring
// mat-vec on an 8-vector starting at 0.  8 lanes per chain (lane = state d),
// v[] replicated in every lane; m[d][j] loads are coalesced across lanes.
// ---------------------------------------------------------------------------
__global__ __launch_bounds__(256) void k3_combine(
    const float* __restrict__ cmat, float* __restrict__ corr)
{
    const int tid = threadIdx.x;
    const int d   = tid & 7;
    const int n   = blockIdx.x * 32 + (tid >> 3);

    float v[8];
#pragma unroll
    for (int j = 0; j < 8; ++j) v[j] = 0.0f;

#pragma unroll 1
    for (int g = 0; g < NCHUNK; ++g) {
        // M_g[d][j] lives at cmat[((g*8 + j)*N_DIM + n)*8 + d]
        const float* mg = cmat + ((size_t)g * 8 * N_DIM + n) * 8 + d;
        float mm[8];
#pragma unroll
        for (int j = 0; j < 8; ++j) mm[j] = mg[(size_t)j * N_DIM * 8];
        float tv[8];
#pragma unroll
        for (int j = 0; j < 8; ++j) tv[j] = mm[j] + v[j];
        float m = tv[0];
#pragma unroll
        for (int j = 1; j < 8; ++j) m = fmaxf(m, tv[j]);
        float ss = 0.0f;
#pragma unroll
        for (int j = 0; j < 8; ++j) ss += fexp2(tv[j] - m);
        const float nv = m + flog2(ss);
        // all-gather the 8 new entries within the 8-lane group
#pragma unroll
        for (int j = 0; j < 8; ++j) v[j] = __shfl(nv, j, 8);
    }
    float m = v[0];
#pragma unroll
    for (int j = 1; j < 8; ++j) m = fmaxf(m, v[j]);
    float ss = 0.0f;
#pragma unroll
    for (int j = 0; j < 8; ++j) ss += fexp2(v[j] - m);
    const float lz2 = m + flog2(ss);                 // base-2 logZ
    if (d == 0) corr[n] = lz2 * LN2_F / (float)T_DIM; // natural-log logZ / T
}

// ---------------------------------------------------------------------------
// K4: out[t][n][c] = y[t][n][c] - corr[n]   (in place over d_out; K1 always
// rewrites d_out first, so this is replay-deterministic)
// ---------------------------------------------------------------------------
__global__ __launch_bounds__(256) void k4_final(
    float* __restrict__ out, const float* __restrict__ corr)
{
    const unsigned int i = blockIdx.x * 256u + threadIdx.x;  // float4 index
    float4* o4 = (float4*)out;
    float4 v = o4[i];
    const unsigned int n = (i / 10u) & (N_DIM - 1);          // 10 float4 / row
    const float cr = corr[n];
    v.x -= cr; v.y -= cr; v.z -= cr; v.w -= cr;
    o4[i] = v;
}

// ---------------------------------------------------------------------------
extern "C" void kernel_launch(void* const* d_in, const int* in_sizes, int n_in,
                              void* d_out, int out_size, void* d_ws, size_t ws_size,
                              hipStream_t stream)
{
    const float* x = (const float*)d_in[0];
    const float* W = (const float*)d_in[1];
    const float* b = (const float*)d_in[2];
    float* y = (float*)d_out;

    float* cmat = (float*)d_ws;                               // 64*8*256*8 f32 = 4 MB
    float* corr = (float*)d_ws + (size_t)NCHUNK * 8 * N_DIM * 8;

    hipLaunchKernelGGL(k1_gemm_tanh, dim3(2048), dim3(256), 0, stream, x, W, b, y);
    hipLaunchKernelGGL(k2_chunks,    dim3(512),  dim3(256), 0, stream, y, cmat);
    hipLaunchKernelGGL(k3_combine,   dim3(8),    dim3(256), 0, stream, cmat, corr);
    hipLaunchKernelGGL(k4_final,     dim3((T_DIM * N_DIM * C_DIM / 4) / 256),
                       dim3(256), 0, stream, y, corr);
}

// Round 2
// 363.120 us; speedup vs baseline: 1.5963x; 1.5963x over previous
//
#include <hip/hip_runtime.h>

#define T_DIM 2048
#define N_DIM 256
#define K_DIM 256
#define C_DIM 40
#define CHUNK 32
#define NCHUNK 64            // T_DIM / CHUNK

#define LOG2E_F 1.44269504088896340736f
#define LN2_F   0.69314718055994530942f
#define NEGBIG  (-1.0e30f)

__device__ __forceinline__ float fexp2(float x) { return exp2f(x); }
__device__ __forceinline__ float flog2(float x) { return log2f(x); }
__device__ __forceinline__ float frcp(float x) { return __frcp_rn(x); }

// ---------------------------------------------------------------------------
// K1: y[row][c] = 5*tanh(dot(x[row], W[c]) + b[c])
// 2 rows per thread; W staged in LDS (40 KB, broadcast ds_read_b128);
// launch_bounds(256,2) so acc[40]x2 + x regs stay in VGPRs (NO spill —
// round-1 version spilled to scratch at VGPR_Count=40 and ran 5x slow).
// ---------------------------------------------------------------------------
#define FMA16(S, A0, A1, A2, A3)                                   \
    S = fmaf(A0.x, w0.x, S); S = fmaf(A0.y, w0.y, S);              \
    S = fmaf(A0.z, w0.z, S); S = fmaf(A0.w, w0.w, S);              \
    S = fmaf(A1.x, w1.x, S); S = fmaf(A1.y, w1.y, S);              \
    S = fmaf(A1.z, w1.z, S); S = fmaf(A1.w, w1.w, S);              \
    S = fmaf(A2.x, w2.x, S); S = fmaf(A2.y, w2.y, S);              \
    S = fmaf(A2.z, w2.z, S); S = fmaf(A2.w, w2.w, S);              \
    S = fmaf(A3.x, w3.x, S); S = fmaf(A3.y, w3.y, S);              \
    S = fmaf(A3.z, w3.z, S); S = fmaf(A3.w, w3.w, S);

__global__ __launch_bounds__(256, 2) void k1_gemm_tanh(
    const float* __restrict__ x, const float* __restrict__ W,
    const float* __restrict__ b, float* __restrict__ y)
{
    __shared__ __align__(16) float Wl[C_DIM * K_DIM];   // 40 KB
    const int tid = threadIdx.x;
    {
        const float4* __restrict__ Wg4 = (const float4*)W;
        float4* Wl4 = (float4*)Wl;
#pragma unroll
        for (int i = 0; i < 10; ++i)                    // 2560 float4 total
            Wl4[i * 256 + tid] = Wg4[i * 256 + tid];
    }
    __syncthreads();

    const size_t rowA = (size_t)blockIdx.x * 512 + tid;
    const float4* __restrict__ xa = (const float4*)(x + rowA * K_DIM);
    const float4* __restrict__ xb = xa + (256 * K_DIM / 4);

    float accA[C_DIM], accB[C_DIM];
#pragma unroll
    for (int c = 0; c < C_DIM; ++c) { const float bc = b[c]; accA[c] = bc; accB[c] = bc; }

#pragma unroll 1
    for (int kt = 0; kt < 16; ++kt) {
        const float4 a0 = xa[kt * 4 + 0], a1 = xa[kt * 4 + 1];
        const float4 a2 = xa[kt * 4 + 2], a3 = xa[kt * 4 + 3];
        const float4 e0 = xb[kt * 4 + 0], e1 = xb[kt * 4 + 1];
        const float4 e2 = xb[kt * 4 + 2], e3 = xb[kt * 4 + 3];
        const float* __restrict__ wb = Wl + kt * 16;
#pragma unroll
        for (int c = 0; c < C_DIM; ++c) {
            const float4 w0 = *(const float4*)(wb + c * K_DIM + 0);
            const float4 w1 = *(const float4*)(wb + c * K_DIM + 4);
            const float4 w2 = *(const float4*)(wb + c * K_DIM + 8);
            const float4 w3 = *(const float4*)(wb + c * K_DIM + 12);
            float sA = accA[c];
            float sB = accB[c];
            FMA16(sA, a0, a1, a2, a3)
            FMA16(sB, e0, e1, e2, e3)
            accA[c] = sA;
            accB[c] = sB;
        }
    }

    float4* __restrict__ ya = (float4*)(y + rowA * C_DIM);
    float4* __restrict__ yb = ya + (256 * C_DIM / 4);
#pragma unroll
    for (int q = 0; q < 10; ++q) {
        float4 oa, ob;
        float* pa = (float*)&oa;
        float* pb = (float*)&ob;
#pragma unroll
        for (int j = 0; j < 4; ++j) {
            {
                const float v = accA[4 * q + j];
                const float e = fexp2(fabsf(v) * (2.0f * LOG2E_F));
                const float t = 1.0f - 2.0f * frcp(e + 1.0f);
                pa[j] = 5.0f * copysignf(t, v);
            }
            {
                const float v = accB[4 * q + j];
                const float e = fexp2(fabsf(v) * (2.0f * LOG2E_F));
                const float t = 1.0f - 2.0f * frcp(e + 1.0f);
                pb[j] = 5.0f * copysignf(t, v);
            }
        }
        ya[q] = oa;
        yb[q] = ob;
    }
}

// ---------------------------------------------------------------------------
// K2: per (chain n, chunk g) propagate the 8x8 log-semiring matrix through
// 32 steps. 8 lanes per task; lane c holds column M[:,c] -> inner loop is
// fully lane-local. Base-2 domain (scores pre-scaled by log2(e)).
// ---------------------------------------------------------------------------
__global__ __launch_bounds__(256) void k2_chunks(
    const float* __restrict__ y, float* __restrict__ cmat)
{
    const int tid  = threadIdx.x;
    const int wave = tid >> 6;
    const int lane = tid & 63;
    const int task = lane >> 3;   // 8 tasks per wave
    const int c    = lane & 7;    // column owned by this lane
    const int g    = blockIdx.x & (NCHUNK - 1);
    const int n    = ((blockIdx.x >> 6) << 5) + (wave << 3) + task;

    float col[8];
#pragma unroll
    for (int j = 0; j < 8; ++j) col[j] = (j == c) ? 0.0f : NEGBIG;

    const float* __restrict__ yp =
        y + ((size_t)(g * CHUNK) * N_DIM + (size_t)n) * C_DIM;

#pragma unroll 1
    for (int s = 0; s < CHUNK; ++s) {
        float sc[C_DIM];
        const float4* p4 = (const float4*)yp;
#pragma unroll
        for (int q = 0; q < 10; ++q) {
            const float4 v = p4[q];
            sc[4 * q + 0] = v.x * LOG2E_F;
            sc[4 * q + 1] = v.y * LOG2E_F;
            sc[4 * q + 2] = v.z * LOG2E_F;
            sc[4 * q + 3] = v.w * LOG2E_F;
        }
        float nc[8];
#pragma unroll
        for (int d = 0; d < 4; ++d) {          // dense rows: lse over 8
            float tv[8];
#pragma unroll
            for (int j = 0; j < 8; ++j) tv[j] = sc[d * 8 + j] + col[j];
            float m = tv[0];
#pragma unroll
            for (int j = 1; j < 8; ++j) m = fmaxf(m, tv[j]);
            float ss = 0.0f;
#pragma unroll
            for (int j = 0; j < 8; ++j) ss += fexp2(tv[j] - m);
            nc[d] = m + flog2(ss);
        }
#pragma unroll
        for (int i = 0; i < 4; ++i) {          // sparse rows: logaddexp of 2
            const float a  = sc[32 + i] + col[i];
            const float bb = sc[36 + i] + col[i + 4];
            const float m  = fmaxf(a, bb);
            const float ss = fexp2(a - m) + fexp2(bb - m);
            nc[4 + i] = m + flog2(ss);
        }
#pragma unroll
        for (int j = 0; j < 8; ++j) col[j] = nc[j];
        yp += (size_t)N_DIM * C_DIM;
    }
    // store M[j][c] at cmat[((g*8 + c)*N_DIM + n)*8 + j]  (contig 8 per lane)
    float* __restrict__ op = cmat + (((size_t)g * 8 + c) * N_DIM + n) * 8;
#pragma unroll
    for (int j = 0; j < 8; ++j) op[j] = col[j];
}

// ---------------------------------------------------------------------------
// K3: per chain, fold the 64 chunk matrices into logZ via log-semiring
// mat-vec on an 8-vector starting at 0.
// ---------------------------------------------------------------------------
__global__ __launch_bounds__(256) void k3_combine(
    const float* __restrict__ cmat, float* __restrict__ corr)
{
    const int tid = threadIdx.x;
    const int d   = tid & 7;
    const int n   = blockIdx.x * 32 + (tid >> 3);

    float v[8];
#pragma unroll
    for (int j = 0; j < 8; ++j) v[j] = 0.0f;

#pragma unroll 1
    for (int g = 0; g < NCHUNK; ++g) {
        const float* mg = cmat + ((size_t)g * 8 * N_DIM + n) * 8 + d;
        float mm[8];
#pragma unroll
        for (int j = 0; j < 8; ++j) mm[j] = mg[(size_t)j * N_DIM * 8];
        float tv[8];
#pragma unroll
        for (int j = 0; j < 8; ++j) tv[j] = mm[j] + v[j];
        float m = tv[0];
#pragma unroll
        for (int j = 1; j < 8; ++j) m = fmaxf(m, tv[j]);
        float ss = 0.0f;
#pragma unroll
        for (int j = 0; j < 8; ++j) ss += fexp2(tv[j] - m);
        const float nv = m + flog2(ss);
#pragma unroll
        for (int j = 0; j < 8; ++j) v[j] = __shfl(nv, j, 8);
    }
    float m = v[0];
#pragma unroll
    for (int j = 1; j < 8; ++j) m = fmaxf(m, v[j]);
    float ss = 0.0f;
#pragma unroll
    for (int j = 0; j < 8; ++j) ss += fexp2(v[j] - m);
    const float lz2 = m + flog2(ss);                 // base-2 logZ
    if (d == 0) corr[n] = lz2 * LN2_F / (float)T_DIM;
}

// ---------------------------------------------------------------------------
// K4: out[t][n][c] = y[t][n][c] - corr[n]
// ---------------------------------------------------------------------------
__global__ __launch_bounds__(256) void k4_final(
    float* __restrict__ out, const float* __restrict__ corr)
{
    const unsigned int i = blockIdx.x * 256u + threadIdx.x;  // float4 index
    float4* o4 = (float4*)out;
    float4 v = o4[i];
    const unsigned int n = (i / 10u) & (N_DIM - 1);          // 10 float4 / row
    const float cr = corr[n];
    v.x -= cr; v.y -= cr; v.z -= cr; v.w -= cr;
    o4[i] = v;
}

// ---------------------------------------------------------------------------
extern "C" void kernel_launch(void* const* d_in, const int* in_sizes, int n_in,
                              void* d_out, int out_size, void* d_ws, size_t ws_size,
                              hipStream_t stream)
{
    const float* x = (const float*)d_in[0];
    const float* W = (const float*)d_in[1];
    const float* b = (const float*)d_in[2];
    float* y = (float*)d_out;

    float* cmat = (float*)d_ws;                               // 64*8*256*8 f32 = 4 MB
    float* corr = (float*)d_ws + (size_t)NCHUNK * 8 * N_DIM * 8;

    hipLaunchKernelGGL(k1_gemm_tanh, dim3(1024), dim3(256), 0, stream, x, W, b, y);
    hipLaunchKernelGGL(k2_chunks,    dim3(512),  dim3(256), 0, stream, y, cmat);
    hipLaunchKernelGGL(k3_combine,   dim3(8),    dim3(256), 0, stream, cmat, corr);
    hipLaunchKernelGGL(k4_final,     dim3((T_DIM * N_DIM * C_DIM / 4) / 256),
                       dim3(256), 0, stream, y, corr);
}